// Round 1
// baseline (4718.643 us; speedup 1.0000x reference)
//
#include <hip/hip_runtime.h>
#include <math.h>

// Problem constants (B,C,H,W) = (4,256,64,64)
#define BATCH 4
#define C_DIM 256
#define HW    4096
#define QT    64   // queries per workgroup (attention)
#define KB    32   // k-tile width (attention)

// ---------------------------------------------------------------------------
// conv1x1: y[b,o,p] = sum_c W[o,c] * x[b,c,p] + bias[o]  (+ res[b,o,p] if res)
// Tiles: 64 o x 64 p per block, 256 threads, 4x4 micro-tile per thread.
// ---------------------------------------------------------------------------
__global__ __launch_bounds__(256) void conv1x1_kernel(
    const float* __restrict__ x, const float* __restrict__ W,
    const float* __restrict__ bias, const float* __restrict__ res,
    float* __restrict__ y)
{
    __shared__ float Xs[64][65];   // [c][p]  pad 65 -> conflict-free
    __shared__ float Ws[64][65];   // [o][c]
    const int b  = blockIdx.z;
    const int o0 = blockIdx.y * 64;
    const int p0 = blockIdx.x * 64;
    const int tid = threadIdx.x;
    const int tx = tid & 15, ty = tid >> 4;
    const float* xb = x + (size_t)b * C_DIM * HW;

    float acc[4][4] = {};
    for (int c0 = 0; c0 < C_DIM; c0 += 64) {
        #pragma unroll
        for (int it = 0; it < 16; ++it) {
            int idx = tid + it * 256;        // 0..4095
            int col = idx & 63, row = idx >> 6;
            Xs[row][col] = xb[(size_t)(c0 + row) * HW + p0 + col];
            Ws[row][col] = W[(size_t)(o0 + row) * C_DIM + c0 + col];
        }
        __syncthreads();
        #pragma unroll 8
        for (int cc = 0; cc < 64; ++cc) {
            float a[4], bb[4];
            #pragma unroll
            for (int i = 0; i < 4; ++i) a[i] = Ws[ty + 16 * i][cc];
            #pragma unroll
            for (int j = 0; j < 4; ++j) bb[j] = Xs[cc][tx + 16 * j];
            #pragma unroll
            for (int i = 0; i < 4; ++i)
                #pragma unroll
                for (int j = 0; j < 4; ++j)
                    acc[i][j] += a[i] * bb[j];
        }
        __syncthreads();
    }
    #pragma unroll
    for (int i = 0; i < 4; ++i) {
        int o = o0 + ty + 16 * i;
        float bv = bias[o];
        size_t base = (size_t)b * C_DIM * HW + (size_t)o * HW + p0;
        #pragma unroll
        for (int j = 0; j < 4; ++j) {
            int p = tx + 16 * j;
            float v = acc[i][j] + bv;
            if (res) v += res[base + p];
            y[base + p] = v;
        }
    }
}

// ---------------------------------------------------------------------------
// Flash-style attention, fp32.
//   S[qi,ki] = sum_c q[c,qi]*k[c,ki];  attn = softmax_k(S);  frs[c,qi] = V@attn^T
// One workgroup per (batch, 64-query tile). Online softmax (m,l per query).
// LDS: q_l 256x68 (68KB), kv_l 36.9KB (K as [c][ki], then V as [ki][c],
//      then output staging), Pt 32x68 (8.7KB). Total ~113KB -> 1 block/CU.
// O accumulator in registers: thread owns a 4-channel x 16-query strip.
// ---------------------------------------------------------------------------
__global__ __launch_bounds__(256) void attn_kernel(
    const float* __restrict__ q, const float* __restrict__ k,
    const float* __restrict__ v, float* __restrict__ frs)
{
    __shared__ __align__(16) float q_l[C_DIM][68];     // [c][qi]
    __shared__ __align__(16) float kv_l[C_DIM * 36];   // K: [c*36+ki] | V/out: [ki*260+c]
    __shared__ __align__(16) float Pt[KB][68];         // [ki][qi] scores then exp'd P
    __shared__ float m_s[QT], l_s[QT], scale_s[QT];

    const int b  = blockIdx.y;
    const int q0 = blockIdx.x * QT;
    const int tid = threadIdx.x;
    const size_t cb = (size_t)b * C_DIM * HW;

    // ---- load Q tile (coalesced over qi)
    #pragma unroll
    for (int it = 0; it < 64; ++it) {
        int idx = tid + it * 256;          // 0..16383
        int qi = idx & 63, c = idx >> 6;
        q_l[c][qi] = q[cb + (size_t)c * HW + q0 + qi];
    }
    if (tid < QT) { m_s[tid] = -INFINITY; l_s[tid] = 0.f; scale_s[tid] = 1.f; }

    // PV ownership: channels c0..c0+3, queries qg*16..qg*16+15
    const int c0 = (tid & 63) * 4;
    const int qg = tid >> 6;               // 0..3 (wave-uniform)
    float acc[16][4] = {};                 // [qi_local][cc]

    // S ownership: 4 queries x 2 keys per thread
    const int ki0 = (tid & 15) * 2;
    const int qi0 = (tid >> 4) * 4;

    for (int t = 0; t < HW / KB; ++t) {
        const int k0 = t * KB;
        // (A) load K tile -> kv_l [c][ki]
        #pragma unroll
        for (int it = 0; it < 32; ++it) {
            int idx = tid + it * 256;      // 0..8191
            int ki = idx & 31, c = idx >> 5;
            kv_l[c * 36 + ki] = k[cb + (size_t)c * HW + k0 + ki];
        }
        __syncthreads();
        // (B) S = q^T k  (register micro-tile 4q x 2k, outer product over c)
        {
            float s00 = 0, s10 = 0, s20 = 0, s30 = 0;
            float s01 = 0, s11 = 0, s21 = 0, s31 = 0;
            #pragma unroll 4
            for (int c = 0; c < C_DIM; ++c) {
                const float4 qv  = *(const float4*)&q_l[c][qi0];
                const float2 kv2 = *(const float2*)&kv_l[c * 36 + ki0];
                s00 += qv.x * kv2.x; s10 += qv.y * kv2.x;
                s20 += qv.z * kv2.x; s30 += qv.w * kv2.x;
                s01 += qv.x * kv2.y; s11 += qv.y * kv2.y;
                s21 += qv.z * kv2.y; s31 += qv.w * kv2.y;
            }
            *(float4*)&Pt[ki0][qi0]     = make_float4(s00, s10, s20, s30);
            *(float4*)&Pt[ki0 + 1][qi0] = make_float4(s01, s11, s21, s31);
        }
        __syncthreads();
        // (C) wave 0: online-softmax update | waves 1-3: load V (transposed)
        if (tid < QT) {
            const int qi = tid;
            float m_old = m_s[qi];
            float rm = m_old;
            #pragma unroll
            for (int ki = 0; ki < KB; ++ki) rm = fmaxf(rm, Pt[ki][qi]);
            float sc = __expf(m_old - rm);   // first tile: exp(-inf)=0
            float rs = 0.f;
            #pragma unroll
            for (int ki = 0; ki < KB; ++ki) {
                float p = __expf(Pt[ki][qi] - rm);
                Pt[ki][qi] = p;
                rs += p;
            }
            l_s[qi] = l_s[qi] * sc + rs;
            m_s[qi] = rm;
            scale_s[qi] = sc;
        } else {
            const int lt = tid - 64;       // 0..191
            #pragma unroll
            for (int it = 0; it < 43; ++it) {   // ceil(8192/192)
                int idx = lt + it * 192;
                if (idx < C_DIM * KB) {
                    int ki = idx & 31, c = idx >> 5;
                    kv_l[ki * 260 + c] = v[cb + (size_t)c * HW + k0 + ki];
                }
            }
        }
        __syncthreads();
        // (D) rescale existing accumulator, then O += V * P^T
        #pragma unroll
        for (int iq = 0; iq < 16; ++iq) {
            const float sc = scale_s[qg * 16 + iq];
            acc[iq][0] *= sc; acc[iq][1] *= sc; acc[iq][2] *= sc; acc[iq][3] *= sc;
        }
        #pragma unroll 2
        for (int ki = 0; ki < KB; ++ki) {
            const float4 vv = *(const float4*)&kv_l[ki * 260 + c0];
            const float ve[4] = {vv.x, vv.y, vv.z, vv.w};
            #pragma unroll
            for (int jq = 0; jq < 4; ++jq) {
                const float4 pv = *(const float4*)&Pt[ki][qg * 16 + jq * 4];  // wave-broadcast
                const float pe[4] = {pv.x, pv.y, pv.z, pv.w};
                #pragma unroll
                for (int e = 0; e < 4; ++e)
                    #pragma unroll
                    for (int cc = 0; cc < 4; ++cc)
                        acc[jq * 4 + e][cc] += ve[cc] * pe[e];
            }
        }
        __syncthreads();   // protect kv_l/Pt before next tile overwrites
    }

    // ---- normalize by l and write out, staged through LDS for coalescing
    #pragma unroll
    for (int iq = 0; iq < 16; ++iq) {
        const float inv_l = 1.0f / l_s[qg * 16 + iq];
        acc[iq][0] *= inv_l; acc[iq][1] *= inv_l; acc[iq][2] *= inv_l; acc[iq][3] *= inv_l;
    }
    for (int g = 0; g < 4; ++g) {
        __syncthreads();
        if (qg == g) {
            #pragma unroll
            for (int iq = 0; iq < 16; ++iq)
                *(float4*)&kv_l[iq * 260 + c0] =
                    make_float4(acc[iq][0], acc[iq][1], acc[iq][2], acc[iq][3]);
        }
        __syncthreads();
        #pragma unroll
        for (int it = 0; it < 16; ++it) {
            int idx = tid + it * 256;      // 0..4095
            int qi = idx & 15, c = idx >> 4;
            frs[cb + (size_t)c * HW + q0 + g * 16 + qi] = kv_l[qi * 260 + c];
        }
    }
}

// ---------------------------------------------------------------------------
// Launch: q/k/v convs -> flash attention -> final conv + residual.
// Workspace: 4 fp32 tensors of B*C*HW = 4*16MB = 64MB.
// ---------------------------------------------------------------------------
extern "C" void kernel_launch(void* const* d_in, const int* in_sizes, int n_in,
                              void* d_out, int out_size, void* d_ws, size_t ws_size,
                              hipStream_t stream)
{
    const float* x_fcc = (const float*)d_in[0];
    const float* x_fss = (const float*)d_in[1];
    const float* w1  = (const float*)d_in[2];
    const float* b1  = (const float*)d_in[3];
    const float* w2  = (const float*)d_in[4];
    const float* b2  = (const float*)d_in[5];
    const float* w3  = (const float*)d_in[6];
    const float* b3  = (const float*)d_in[7];
    const float* wrs = (const float*)d_in[8];
    const float* brs = (const float*)d_in[9];
    float* out = (float*)d_out;

    const size_t tensor_elems = (size_t)BATCH * C_DIM * HW;
    float* qbuf = (float*)d_ws;
    float* kbuf = qbuf + tensor_elems;
    float* vbuf = kbuf + tensor_elems;
    float* fbuf = vbuf + tensor_elems;

    dim3 cgrid(HW / 64, C_DIM / 64, BATCH);
    conv1x1_kernel<<<cgrid, 256, 0, stream>>>(x_fcc, w1, b1, nullptr, qbuf);
    conv1x1_kernel<<<cgrid, 256, 0, stream>>>(x_fss, w2, b2, nullptr, kbuf);
    conv1x1_kernel<<<cgrid, 256, 0, stream>>>(x_fss, w3, b3, nullptr, vbuf);

    dim3 agrid(HW / QT, BATCH);
    attn_kernel<<<agrid, 256, 0, stream>>>(qbuf, kbuf, vbuf, fbuf);

    conv1x1_kernel<<<cgrid, 256, 0, stream>>>(fbuf, wrs, brs, x_fcc, out);
}

// Round 2
// 588.192 us; speedup vs baseline: 8.0223x; 8.0223x over previous
//
#include <hip/hip_runtime.h>
#include <math.h>
#include <stdint.h>

#define BATCH 4
#define C_DIM 256
#define HW    4096
#define KT    64
#define NTILES (HW / KT)
#define LOG2E 1.44269504088896340736f

typedef _Float16 half8 __attribute__((ext_vector_type(8)));
typedef float f32x4 __attribute__((ext_vector_type(4)));
typedef unsigned int u32;

#define MFMA16(a, b, c) __builtin_amdgcn_mfma_f32_16x16x32_f16(a, b, c, 0, 0, 0)

// async global->LDS, 16B per lane; LDS dst wave-uniform base + lane*16,
// global src per-lane (pre-swizzled source trick, m173)
#define GLL16(gsrc, ldst) \
  __builtin_amdgcn_global_load_lds((const __attribute__((address_space(1))) u32*)(const void*)(gsrc), \
                                   (__attribute__((address_space(3))) u32*)(void*)(ldst), 16, 0, 0)

// ---------------------------------------------------------------------------
// conv1x1 (fp32 compute). MODE 0: fp32 natural + residual -> yf
//                         MODE 1: fp16 hi/lo TRANSPOSED [b][p][c] -> yh, yl
//                         MODE 2: fp16 hi natural [b][c][p] -> yh
// ---------------------------------------------------------------------------
template<int MODE>
__global__ __launch_bounds__(256) void conv1x1_k(
    const float* __restrict__ x, const float* __restrict__ W,
    const float* __restrict__ bias, const float* __restrict__ res,
    float* __restrict__ yf, _Float16* __restrict__ yh, _Float16* __restrict__ yl)
{
    __shared__ float Xs[64][65];
    __shared__ float Ws[64][65];
    const int b  = blockIdx.z;
    const int o0 = blockIdx.y * 64;
    const int p0 = blockIdx.x * 64;
    const int tid = threadIdx.x;
    const int tx = tid & 15, ty = tid >> 4;
    const float* xb = x + (size_t)b * C_DIM * HW;

    float acc[4][4] = {};
    for (int c0 = 0; c0 < C_DIM; c0 += 64) {
        #pragma unroll
        for (int it = 0; it < 16; ++it) {
            int idx = tid + it * 256;
            int col = idx & 63, row = idx >> 6;
            Xs[row][col] = xb[(size_t)(c0 + row) * HW + p0 + col];
            Ws[row][col] = W[(size_t)(o0 + row) * C_DIM + c0 + col];
        }
        __syncthreads();
        #pragma unroll 8
        for (int cc = 0; cc < 64; ++cc) {
            float a[4], bb[4];
            #pragma unroll
            for (int i = 0; i < 4; ++i) a[i] = Ws[ty + 16 * i][cc];
            #pragma unroll
            for (int j = 0; j < 4; ++j) bb[j] = Xs[cc][tx + 16 * j];
            #pragma unroll
            for (int i = 0; i < 4; ++i)
                #pragma unroll
                for (int j = 0; j < 4; ++j)
                    acc[i][j] += a[i] * bb[j];
        }
        __syncthreads();
    }

    if (MODE == 0) {
        #pragma unroll
        for (int i = 0; i < 4; ++i) {
            int o = o0 + ty + 16 * i;
            float bv = bias[o];
            size_t base = (size_t)b * C_DIM * HW + (size_t)o * HW + p0;
            #pragma unroll
            for (int j = 0; j < 4; ++j) {
                int p = tx + 16 * j;
                float v = acc[i][j] + bv;
                if (res) v += res[base + p];
                yf[base + p] = v;
            }
        }
    } else if (MODE == 1) {
        // stage val into Xs[p_local][o_local], then split-write transposed
        #pragma unroll
        for (int i = 0; i < 4; ++i) {
            float bv = bias[o0 + ty + 16 * i];
            #pragma unroll
            for (int j = 0; j < 4; ++j)
                Xs[tx + 16 * j][ty + 16 * i] = acc[i][j] + bv;
        }
        __syncthreads();
        const int p_l = tid >> 2, och = (tid & 3) * 16;
        _Float16 hb[16], lb[16];
        #pragma unroll
        for (int e = 0; e < 16; ++e) {
            float v = Xs[p_l][och + e];
            _Float16 h = (_Float16)v;
            hb[e] = h;
            lb[e] = (_Float16)(v - (float)h);
        }
        size_t g = ((size_t)(b * HW + p0 + p_l)) * C_DIM + o0 + och;
        *(uint4*)(yh + g)     = *(uint4*)(hb);
        *(uint4*)(yh + g + 8) = *(uint4*)(hb + 8);
        *(uint4*)(yl + g)     = *(uint4*)(lb);
        *(uint4*)(yl + g + 8) = *(uint4*)(lb + 8);
    } else {
        // natural fp16
        #pragma unroll
        for (int i = 0; i < 4; ++i) {
            float bv = bias[o0 + ty + 16 * i];
            #pragma unroll
            for (int j = 0; j < 4; ++j)
                Xs[ty + 16 * i][tx + 16 * j] = acc[i][j] + bv;
        }
        __syncthreads();
        const int o_l = tid >> 2, pch = (tid & 3) * 16;
        _Float16 hb[16];
        #pragma unroll
        for (int e = 0; e < 16; ++e) hb[e] = (_Float16)Xs[o_l][pch + e];
        size_t g = ((size_t)(b * C_DIM + o0 + o_l)) * HW + p0 + pch;
        *(uint4*)(yh + g)     = *(uint4*)(hb);
        *(uint4*)(yh + g + 8) = *(uint4*)(hb + 8);
    }
}

// ---------------------------------------------------------------------------
// MFMA flash attention. WG = (batch, 64 queries), 4 waves, wave w owns
// queries [w*16, w*16+16) for QK^T/softmax and channels [w*64, w*64+64) for PV.
// QK^T: fp16x3 split (qh*kh + ql*kh + qh*kl). PV: plain fp16.
// K_lds [ki][c] swz, V_lds [c][ki] swz (double buffered), P_lds [qi][ki] swz.
// ---------------------------------------------------------------------------
__global__ __launch_bounds__(256, 1) void attn_mfma(
    const _Float16* __restrict__ qTh, const _Float16* __restrict__ qTl,
    const _Float16* __restrict__ kTh, const _Float16* __restrict__ kTl,
    const _Float16* __restrict__ vh, float* __restrict__ frs)
{
    __shared__ __align__(1024) char smem[139776];
    char* const KH = smem;             // 32KB  [ki 64][c 256] fp16, swz
    char* const KL = smem + 32768;     // 32KB
    char* const V0 = smem + 65536;     // 32KB  [c 256][ki 64] fp16, swz
    char* const V1 = smem + 98304;     // 32KB
    char* const PB = smem + 131072;    // 8KB   [qi 64][ki 64] fp16, swz
    float* const SCb = (float*)(smem + 139264);  // 64 floats
    float* const LSb = SCb + 64;                 // 64 floats

    const int tid  = threadIdx.x;
    const int lane = tid & 63;
    const int w    = tid >> 6;
    const int l15  = lane & 15, l4 = lane >> 4;
    const int b    = blockIdx.y;
    const int q0   = blockIdx.x * 64;

    // ---- Q fragments to registers (A-frag: row=lane&15, k=(lane>>4)*8+i)
    half8 qh[8], ql[8];
    {
        const size_t base = ((size_t)b * HW + (q0 + w * 16 + l15)) * C_DIM + l4 * 8;
        #pragma unroll
        for (int s = 0; s < 8; ++s) {
            qh[s] = *(const half8*)(qTh + base + s * 32);
            ql[s] = *(const half8*)(qTl + base + s * 32);
        }
    }

    const int krow_l = lane >> 5, ks5 = lane & 31;   // K: 1KB seg = 2 rows x 512B
    const int vrow_l = lane >> 3, vs3 = lane & 7;    // V: 1KB seg = 8 rows x 128B

    auto stageK = [&](int t) {
        const int k0 = t * KT;
        #pragma unroll
        for (int i = 0; i < 8; ++i) {
            const int r0 = w * 16 + i * 2;
            const int row = r0 + krow_l;
            const int cc = (ks5 ^ (row & 7)) * 8;     // inverse-swizzled source
            const size_t gs = ((size_t)b * HW + k0 + row) * C_DIM + cc;
            GLL16(kTh + gs, KH + r0 * 512);
            GLL16(kTl + gs, KL + r0 * 512);
        }
    };
    auto stageV = [&](int t, char* VB) {
        const int k0 = t * KT;
        #pragma unroll
        for (int i = 0; i < 8; ++i) {
            const int c0w = w * 64 + i * 8;
            const int c = c0w + vrow_l;
            const int kk = (vs3 ^ (c & 7)) * 8;
            const size_t gs = ((size_t)b * C_DIM + c) * HW + k0 + kk;
            GLL16(vh + gs, VB + c0w * 128);
        }
    };

    stageK(0);
    stageV(0, V0);

    f32x4 accp[4][4];
    #pragma unroll
    for (int mt = 0; mt < 4; ++mt)
        #pragma unroll
        for (int nt = 0; nt < 4; ++nt) {
            f32x4 z = {0.f, 0.f, 0.f, 0.f};
            accp[mt][nt] = z;
        }
    float m_run[4], l_run[4];
    #pragma unroll
    for (int r = 0; r < 4; ++r) { m_run[r] = -INFINITY; l_run[r] = 0.f; }

    for (int t = 0; t < NTILES; ++t) {
        __syncthreads();   // B1: K(t)/V(t) staged (drains vmcnt), P(t-1) consumed

        // ---- QK^T : S[16q x 64k], fp16x3
        f32x4 sacc[4];
        #pragma unroll
        for (int nt = 0; nt < 4; ++nt) {
            f32x4 z = {0.f, 0.f, 0.f, 0.f};
            sacc[nt] = z;
        }
        #pragma unroll
        for (int s = 0; s < 8; ++s) {
            const int coff = s * 64 + l4 * 16;   // byte offset of lane's c-run
            #pragma unroll
            for (int nt = 0; nt < 4; ++nt) {
                const int ki = nt * 16 + l15;
                const int sw = (ki & 7) << 4;
                half8 kf = *(const half8*)(KH + ki * 512 + (coff ^ sw));
                half8 lf = *(const half8*)(KL + ki * 512 + (coff ^ sw));
                sacc[nt] = MFMA16(qh[s], kf, sacc[nt]);
                sacc[nt] = MFMA16(ql[s], kf, sacc[nt]);
                sacc[nt] = MFMA16(qh[s], lf, sacc[nt]);
            }
        }

        // ---- online softmax (rows r: qi = w*16 + l4*4 + r; cols ki = nt*16+l15)
        #pragma unroll
        for (int r = 0; r < 4; ++r) {
            float mx = fmaxf(fmaxf(sacc[0][r], sacc[1][r]), fmaxf(sacc[2][r], sacc[3][r]));
            mx = fmaxf(mx, __shfl_xor(mx, 1));
            mx = fmaxf(mx, __shfl_xor(mx, 2));
            mx = fmaxf(mx, __shfl_xor(mx, 4));
            mx = fmaxf(mx, __shfl_xor(mx, 8));
            const float mnew = fmaxf(m_run[r], mx);
            const float sc = exp2f((m_run[r] - mnew) * LOG2E);
            const int qrow = w * 16 + l4 * 4 + r;
            float rs = 0.f;
            #pragma unroll
            for (int nt = 0; nt < 4; ++nt) {
                float p = exp2f((sacc[nt][r] - mnew) * LOG2E);
                rs += p;
                const int ki = nt * 16 + l15;
                *(_Float16*)(PB + qrow * 128 + ((ki * 2) ^ ((qrow & 7) << 4))) = (_Float16)p;
            }
            rs += __shfl_xor(rs, 1); rs += __shfl_xor(rs, 2);
            rs += __shfl_xor(rs, 4); rs += __shfl_xor(rs, 8);
            l_run[r] = l_run[r] * sc + rs;
            m_run[r] = mnew;
            if (l15 == 0) SCb[qrow] = sc;
        }
        __syncthreads();   // B2: P/SC visible; all waves done reading KH/KL

        if (t + 1 < NTILES) {
            stageK(t + 1);
            stageV(t + 1, ((t + 1) & 1) ? V1 : V0);
        }

        // ---- PV: acc[c,qi] rescale + V @ P^T
        const char* VB = (t & 1) ? V1 : V0;
        float scv[4];
        #pragma unroll
        for (int nt = 0; nt < 4; ++nt) scv[nt] = SCb[nt * 16 + l15];
        #pragma unroll
        for (int mt = 0; mt < 4; ++mt)
            #pragma unroll
            for (int nt = 0; nt < 4; ++nt)
                #pragma unroll
                for (int r = 0; r < 4; ++r)
                    accp[mt][nt][r] *= scv[nt];
        #pragma unroll
        for (int ks = 0; ks < 2; ++ks) {
            const int kio = ks * 64 + l4 * 16;   // ki byte offset
            half8 pf[4];
            #pragma unroll
            for (int nt = 0; nt < 4; ++nt) {
                const int qi = nt * 16 + l15;
                pf[nt] = *(const half8*)(PB + qi * 128 + (kio ^ ((qi & 7) << 4)));
            }
            #pragma unroll
            for (int mt = 0; mt < 4; ++mt) {
                const int c = w * 64 + mt * 16 + l15;
                half8 vf = *(const half8*)(VB + c * 128 + (kio ^ ((c & 7) << 4)));
                #pragma unroll
                for (int nt = 0; nt < 4; ++nt)
                    accp[mt][nt] = MFMA16(vf, pf[nt], accp[mt][nt]);
            }
        }
    }

    // ---- epilogue: /l, stage to LDS (stride 68 floats), coalesced-ish write
    if (l15 == 0) {
        #pragma unroll
        for (int r = 0; r < 4; ++r) LSb[w * 16 + l4 * 4 + r] = l_run[r];
    }
    __syncthreads();   // all PV done; smem front region reusable
    float* stage = (float*)smem;   // [256][68] fp32 = 69632 B
    float linv[4];
    #pragma unroll
    for (int nt = 0; nt < 4; ++nt) linv[nt] = 1.0f / LSb[nt * 16 + l15];
    #pragma unroll
    for (int mt = 0; mt < 4; ++mt)
        #pragma unroll
        for (int nt = 0; nt < 4; ++nt)
            #pragma unroll
            for (int r = 0; r < 4; ++r)
                stage[(w * 64 + mt * 16 + l4 * 4 + r) * 68 + nt * 16 + l15] =
                    accp[mt][nt][r] * linv[nt];
    __syncthreads();
    {
        const float4* srow = (const float4*)(stage + tid * 68);
        float4* drow = (float4*)(frs + ((size_t)b * C_DIM + tid) * HW + q0);
        #pragma unroll
        for (int j = 0; j < 16; ++j) drow[j] = srow[j];
    }
}

// ---------------------------------------------------------------------------
extern "C" void kernel_launch(void* const* d_in, const int* in_sizes, int n_in,
                              void* d_out, int out_size, void* d_ws, size_t ws_size,
                              hipStream_t stream)
{
    const float* x_fcc = (const float*)d_in[0];
    const float* x_fss = (const float*)d_in[1];
    const float* w1  = (const float*)d_in[2];
    const float* b1  = (const float*)d_in[3];
    const float* w2  = (const float*)d_in[4];
    const float* b2  = (const float*)d_in[5];
    const float* w3  = (const float*)d_in[6];
    const float* b3  = (const float*)d_in[7];
    const float* wrs = (const float*)d_in[8];
    const float* brs = (const float*)d_in[9];
    float* out = (float*)d_out;

    const size_t NE = (size_t)BATCH * C_DIM * HW;   // 4.19M elems
    char* ws = (char*)d_ws;
    _Float16* qTh = (_Float16*)(ws);
    _Float16* qTl = (_Float16*)(ws + 2 * NE);
    _Float16* kTh = (_Float16*)(ws + 4 * NE);
    _Float16* kTl = (_Float16*)(ws + 6 * NE);
    _Float16* vhb = (_Float16*)(ws + 8 * NE);
    float*    fbuf = (float*)  (ws + 10 * NE);

    dim3 cgrid(HW / 64, C_DIM / 64, BATCH);
    conv1x1_k<1><<<cgrid, 256, 0, stream>>>(x_fcc, w1, b1, nullptr, nullptr, qTh, qTl);
    conv1x1_k<1><<<cgrid, 256, 0, stream>>>(x_fss, w2, b2, nullptr, nullptr, kTh, kTl);
    conv1x1_k<2><<<cgrid, 256, 0, stream>>>(x_fss, w3, b3, nullptr, nullptr, vhb, nullptr);

    dim3 agrid(HW / 64, BATCH);
    attn_mfma<<<agrid, 256, 0, stream>>>(qTh, qTl, kTh, kTl, vhb, fbuf);

    conv1x1_k<0><<<cgrid, 256, 0, stream>>>(fbuf, wrs, brs, x_fcc, out, nullptr, nullptr);
}

// Round 4
// 399.335 us; speedup vs baseline: 11.8162x; 1.4729x over previous
//
#include <hip/hip_runtime.h>
#include <math.h>
#include <stdint.h>

#define BATCH 4
#define C_DIM 256
#define HW    4096
#define KT    32          // attention k-tile
#define LOG2E 1.44269504088896340736f

typedef _Float16 half8 __attribute__((ext_vector_type(8)));
typedef float f32x4 __attribute__((ext_vector_type(4)));
typedef unsigned int u32;

#define MFMA16(a, b, c) __builtin_amdgcn_mfma_f32_16x16x32_f16(a, b, c, 0, 0, 0)

#define GLL16(gsrc, ldst) \
  __builtin_amdgcn_global_load_lds((const __attribute__((address_space(1))) u32*)(const void*)(gsrc), \
                                   (__attribute__((address_space(3))) u32*)(void*)(ldst), 16, 0, 0)

// ---------------------------------------------------------------------------
// cvt: x f32 [b][c][p] -> xT hi/lo fp16 [b][p][c]   (transpose + split)
// ---------------------------------------------------------------------------
__global__ __launch_bounds__(256) void cvt_tsplit(
    const float* __restrict__ x, _Float16* __restrict__ xh, _Float16* __restrict__ xl)
{
    __shared__ float Xs[64][65];
    const int b = blockIdx.z, c0 = blockIdx.y * 64, p0 = blockIdx.x * 64;
    const int tid = threadIdx.x;
    #pragma unroll
    for (int it = 0; it < 16; ++it) {
        int idx = tid + it * 256;
        int row = idx >> 6, col = idx & 63;
        Xs[row][col] = x[((size_t)b * C_DIM + c0 + row) * HW + p0 + col];
    }
    __syncthreads();
    #pragma unroll
    for (int it = 0; it < 16; ++it) {
        int idx = tid + it * 256;
        int p_l = idx >> 6, c_l = idx & 63;
        float v = Xs[c_l][p_l];
        _Float16 h = (_Float16)v;
        size_t g = ((size_t)b * HW + p0 + p_l) * C_DIM + c0 + c_l;
        xh[g] = h;
        xl[g] = (_Float16)(v - (float)h);
    }
}

// ---------------------------------------------------------------------------
// wsplit: 4 weight matrices f32 [256][256] -> Wh/Wl fp16 (natural layout)
// ---------------------------------------------------------------------------
__global__ __launch_bounds__(256) void wsplit(
    const float* __restrict__ w1, const float* __restrict__ w2,
    const float* __restrict__ w3, const float* __restrict__ w4,
    _Float16* __restrict__ Wh, _Float16* __restrict__ Wl)
{
    const int m = blockIdx.y;
    const float* src = (m == 0) ? w1 : (m == 1) ? w2 : (m == 2) ? w3 : w4;
    const int i = blockIdx.x * 256 + threadIdx.x;   // grid.x = 256 -> 65536
    float v = src[i];
    _Float16 h = (_Float16)v;
    Wh[m * 65536 + i] = h;
    Wl[m * 65536 + i] = (_Float16)(v - (float)h);
}

// ---------------------------------------------------------------------------
// conv1x1 as split-fp16 MFMA GEMM.  Y[o][p] = sum_c W[o][c] X^T[p][c]
// Block: 64 o x 128 p, 4 waves, K=256 in 4 steps of 64. LDS 48KB -> 3 blk/CU.
// MODE 0: out [p][o] hi/lo fp16 (for q/k);  A=W, B=X  (D rows=o, cols=p)
// MODE 1: out [o][p] fp16 hi    (for v);    A=X, B=W  (D rows=p, cols=o)
// MODE 2: out [o][p] f32 + bias + residual; A=X, B=W
// ---------------------------------------------------------------------------
template<int MODE>
__global__ __launch_bounds__(256, 3) void conv_mfma(
    const _Float16* __restrict__ Wh, const _Float16* __restrict__ Wl,
    const _Float16* __restrict__ Xh, const _Float16* __restrict__ Xl,
    const float* __restrict__ bias,
    const float* __restrict__ res, float* __restrict__ outf,
    _Float16* __restrict__ oh, _Float16* __restrict__ ol)
{
    __shared__ __align__(1024) char smem[49152];
    char* const AH = smem;              // W tile [64][128B]
    char* const AL = smem + 8192;
    char* const BH = smem + 16384;      // X tile [128][128B]
    char* const BL = smem + 32768;

    const int tid = threadIdx.x;
    const int lane = tid & 63;
    const int w = tid >> 6;
    const int l15 = lane & 15, l4 = lane >> 4;
    const int o0 = blockIdx.y * 64;
    const int gp0 = blockIdx.x * 128;   // global p (includes batch)

    auto stage = [&](int ks) {
        const int kc0 = ks * 64;
        #pragma unroll
        for (int i = 0; i < 2; ++i) {   // W: 8KB/half -> 8 calls, 2 per wave
            const int r0 = w * 16 + i * 8;
            const int row = r0 + (lane >> 3);
            const int cc = ((lane & 7) ^ (row & 7)) * 8 + kc0;
            const size_t g = (size_t)(o0 + row) * C_DIM + cc;
            GLL16(Wh + g, AH + r0 * 128);
            GLL16(Wl + g, AL + r0 * 128);
        }
        #pragma unroll
        for (int i = 0; i < 4; ++i) {   // X: 16KB/half -> 16 calls, 4 per wave
            const int r0 = w * 32 + i * 8;
            const int p = r0 + (lane >> 3);
            const int cc = ((lane & 7) ^ (p & 7)) * 8 + kc0;
            const size_t g = (size_t)(gp0 + p) * C_DIM + cc;
            GLL16(Xh + g, BH + r0 * 128);
            GLL16(Xl + g, BL + r0 * 128);
        }
    };

    f32x4 acc[4][4];   // MODE0 uses [4][2]; MODE1/2 use [2][4]
    #pragma unroll
    for (int i = 0; i < 4; ++i)
        #pragma unroll
        for (int j = 0; j < 4; ++j) {
            f32x4 z = {0.f, 0.f, 0.f, 0.f};
            acc[i][j] = z;
        }

    stage(0);
    for (int ks = 0; ks < 4; ++ks) {
        __syncthreads();   // staged data ready (drains vmcnt)
        #pragma unroll
        for (int s = 0; s < 2; ++s) {
            const int coff = s * 64 + l4 * 16;
            if (MODE == 0) {
                half8 ah[4], al[4], bh[2], bl[2];
                #pragma unroll
                for (int mt = 0; mt < 4; ++mt) {
                    const int ol_ = mt * 16 + l15;
                    const int sw = (ol_ & 7) << 4;
                    ah[mt] = *(const half8*)(AH + ol_ * 128 + (coff ^ sw));
                    al[mt] = *(const half8*)(AL + ol_ * 128 + (coff ^ sw));
                }
                #pragma unroll
                for (int nt = 0; nt < 2; ++nt) {
                    const int pl_ = w * 32 + nt * 16 + l15;
                    const int sw = (pl_ & 7) << 4;
                    bh[nt] = *(const half8*)(BH + pl_ * 128 + (coff ^ sw));
                    bl[nt] = *(const half8*)(BL + pl_ * 128 + (coff ^ sw));
                }
                #pragma unroll
                for (int mt = 0; mt < 4; ++mt)
                    #pragma unroll
                    for (int nt = 0; nt < 2; ++nt) {
                        acc[mt][nt] = MFMA16(ah[mt], bh[nt], acc[mt][nt]);
                        acc[mt][nt] = MFMA16(al[mt], bh[nt], acc[mt][nt]);
                        acc[mt][nt] = MFMA16(ah[mt], bl[nt], acc[mt][nt]);
                    }
            } else {
                half8 ah[2], al[2], bh[4], bl[4];
                #pragma unroll
                for (int mt = 0; mt < 2; ++mt) {
                    const int pl_ = w * 32 + mt * 16 + l15;
                    const int sw = (pl_ & 7) << 4;
                    ah[mt] = *(const half8*)(BH + pl_ * 128 + (coff ^ sw));
                    al[mt] = *(const half8*)(BL + pl_ * 128 + (coff ^ sw));
                }
                #pragma unroll
                for (int nt = 0; nt < 4; ++nt) {
                    const int ol_ = nt * 16 + l15;
                    const int sw = (ol_ & 7) << 4;
                    bh[nt] = *(const half8*)(AH + ol_ * 128 + (coff ^ sw));
                    bl[nt] = *(const half8*)(AL + ol_ * 128 + (coff ^ sw));
                }
                #pragma unroll
                for (int mt = 0; mt < 2; ++mt)
                    #pragma unroll
                    for (int nt = 0; nt < 4; ++nt) {
                        acc[mt][nt] = MFMA16(ah[mt], bh[nt], acc[mt][nt]);
                        acc[mt][nt] = MFMA16(al[mt], bh[nt], acc[mt][nt]);
                        acc[mt][nt] = MFMA16(ah[mt], bl[nt], acc[mt][nt]);
                    }
            }
        }
        __syncthreads();   // all LDS reads done
        if (ks < 3) stage(ks + 1);
    }

    if (MODE == 0) {
        // D[o][p]: lane col p = w*32+nt*16+l15; rows o = mt*16+l4*4+r
        float bv[4][4];
        #pragma unroll
        for (int mt = 0; mt < 4; ++mt)
            #pragma unroll
            for (int r = 0; r < 4; ++r)
                bv[mt][r] = bias[o0 + mt * 16 + l4 * 4 + r];
        #pragma unroll
        for (int nt = 0; nt < 2; ++nt) {
            const size_t p = gp0 + w * 32 + nt * 16 + l15;
            #pragma unroll
            for (int mt = 0; mt < 4; ++mt) {
                _Float16 hb[4], lb[4];
                #pragma unroll
                for (int r = 0; r < 4; ++r) {
                    float v = acc[mt][nt][r] + bv[mt][r];
                    _Float16 h = (_Float16)v;
                    hb[r] = h;
                    lb[r] = (_Float16)(v - (float)h);
                }
                const size_t g = p * C_DIM + o0 + mt * 16 + l4 * 4;
                *(uint2*)(oh + g) = *(uint2*)hb;
                *(uint2*)(ol + g) = *(uint2*)lb;
            }
        }
    } else {
        // D[p][o]: lane col o = nt*16+l15; rows p = w*32+mt*16+l4*4+r
        float bv[4];
        #pragma unroll
        for (int nt = 0; nt < 4; ++nt) bv[nt] = bias[o0 + nt * 16 + l15];
        const int b = gp0 >> 12;
        #pragma unroll
        for (int mt = 0; mt < 2; ++mt) {
            const int sp = (gp0 & 4095) + w * 32 + mt * 16 + l4 * 4;
            #pragma unroll
            for (int nt = 0; nt < 4; ++nt) {
                const int o = o0 + nt * 16 + l15;
                const size_t base = ((size_t)b * C_DIM + o) * HW + sp;
                if (MODE == 1) {
                    _Float16 hb[4];
                    #pragma unroll
                    for (int r = 0; r < 4; ++r)
                        hb[r] = (_Float16)(acc[mt][nt][r] + bv[nt]);
                    *(uint2*)(oh + base) = *(uint2*)hb;
                } else {
                    f32x4 rv = *(const f32x4*)(res + base);
                    f32x4 vv;
                    #pragma unroll
                    for (int r = 0; r < 4; ++r) vv[r] = acc[mt][nt][r] + bv[nt] + rv[r];
                    *(f32x4*)(outf + base) = vv;
                }
            }
        }
    }
}

// ---------------------------------------------------------------------------
// MFMA flash attention, KT=32, K-range split x2 across WGs.
// WG = (batch, k-half, 64 queries), 4 waves. LDS ~69KB -> 2 blocks/CU.
// Outputs UNNORMALIZED partial O (f32, [q][c]) + (m,l) per q.
// khalf=0 -> OpA (ws), khalf=1 -> OpB (d_out used as scratch).
// ---------------------------------------------------------------------------
__global__ __launch_bounds__(256, 2) void attn_mfma(
    const _Float16* __restrict__ qTh, const _Float16* __restrict__ qTl,
    const _Float16* __restrict__ kTh, const _Float16* __restrict__ kTl,
    const _Float16* __restrict__ vh,
    float* __restrict__ OpA, float* __restrict__ OpB, float2* __restrict__ ml)
{
    __shared__ __align__(1024) char smem[71168];
    char* const KH = smem;              // 16KB [ki 32][c 256] fp16 swz
    char* const KL = smem + 16384;
    char* const V0 = smem + 32768;      // 16KB [c 256][ki 32] fp16 swz
    char* const V1 = smem + 49152;
    char* const PB = smem + 65536;      // 64 x 80B  [qi][ki] fp16
    float* const SCb = (float*)(smem + 70656);   // 64 floats

    const int raw = blockIdx.x;                  // 512 WGs; raw%8 -> XCD
    const int b2h = raw & 7;
    const int b = b2h >> 1, khalf = b2h & 1;
    const int q0 = (raw >> 3) * 64;
    const int kbase = khalf * 2048;

    const int tid = threadIdx.x;
    const int lane = tid & 63;
    const int w = tid >> 6;
    const int l15 = lane & 15, l4 = lane >> 4;
    const size_t cb = (size_t)b * C_DIM * HW;

    // Q fragments (A-frag: row=lane&15 -> q, k-run over c)
    half8 qh[8], ql[8];
    {
        const size_t base = ((size_t)b * HW + (q0 + w * 16 + l15)) * C_DIM + l4 * 8;
        #pragma unroll
        for (int s = 0; s < 8; ++s) {
            qh[s] = *(const half8*)(qTh + base + s * 32);
            ql[s] = *(const half8*)(qTl + base + s * 32);
        }
    }

    auto stageK = [&](int t) {
        const int k0 = kbase + t * KT;
        #pragma unroll
        for (int i = 0; i < 4; ++i) {
            const int r0 = w * 8 + i * 2;
            const int row = r0 + (lane >> 5);
            const int cc = ((lane & 31) ^ (row & 7)) * 8;
            const size_t gs = ((size_t)b * HW + k0 + row) * C_DIM + cc;
            GLL16(kTh + gs, KH + r0 * 512);
            GLL16(kTl + gs, KL + r0 * 512);
        }
    };
    auto stageV = [&](int t, char* VB) {
        const int k0 = kbase + t * KT;
        #pragma unroll
        for (int i = 0; i < 4; ++i) {
            const int c0w = w * 64 + i * 16;
            const int c = c0w + (lane >> 2);
            const int kk = ((lane & 3) ^ (c & 3)) * 8;
            const size_t gs = (cb + (size_t)c * HW) + k0 + kk;
            GLL16(vh + gs, VB + c0w * 64);
        }
    };

    stageK(0);
    stageV(0, V0);

    f32x4 accp[4][4];
    #pragma unroll
    for (int mt = 0; mt < 4; ++mt)
        #pragma unroll
        for (int nt = 0; nt < 4; ++nt) {
            f32x4 z = {0.f, 0.f, 0.f, 0.f};
            accp[mt][nt] = z;
        }
    float m_run[4], l_run[4];
    #pragma unroll
    for (int r = 0; r < 4; ++r) { m_run[r] = -INFINITY; l_run[r] = 0.f; }

    for (int t = 0; t < 2048 / KT; ++t) {
        __syncthreads();   // B1: K(t)/V(t) staged; P(t-1) consumed

        // ---- QK^T: S[16q x 32k], fp16x3 split
        f32x4 sacc[2];
        #pragma unroll
        for (int nt = 0; nt < 2; ++nt) {
            f32x4 z = {0.f, 0.f, 0.f, 0.f};
            sacc[nt] = z;
        }
        #pragma unroll
        for (int s = 0; s < 8; ++s) {
            const int coff = s * 64 + l4 * 16;
            #pragma unroll
            for (int nt = 0; nt < 2; ++nt) {
                const int ki = nt * 16 + l15;
                const int sw = (ki & 7) << 4;
                half8 kf = *(const half8*)(KH + ki * 512 + (coff ^ sw));
                half8 lf = *(const half8*)(KL + ki * 512 + (coff ^ sw));
                sacc[nt] = MFMA16(qh[s], kf, sacc[nt]);
                sacc[nt] = MFMA16(ql[s], kf, sacc[nt]);
                sacc[nt] = MFMA16(qh[s], lf, sacc[nt]);
            }
        }

        // ---- online softmax (qrow = w*16 + l4*4 + r; ki = nt*16 + l15)
        #pragma unroll
        for (int r = 0; r < 4; ++r) {
            float mx = fmaxf(sacc[0][r], sacc[1][r]);
            mx = fmaxf(mx, __shfl_xor(mx, 1));
            mx = fmaxf(mx, __shfl_xor(mx, 2));
            mx = fmaxf(mx, __shfl_xor(mx, 4));
            mx = fmaxf(mx, __shfl_xor(mx, 8));
            const float mnew = fmaxf(m_run[r], mx);
            const float sc = exp2f((m_run[r] - mnew) * LOG2E);
            const int qrow = w * 16 + l4 * 4 + r;
            float rs = 0.f;
            #pragma unroll
            for (int nt = 0; nt < 2; ++nt) {
                float p = exp2f((sacc[nt][r] - mnew) * LOG2E);
                rs += p;
                const int ki = nt * 16 + l15;
                *(_Float16*)(PB + qrow * 80 + ki * 2) = (_Float16)p;
            }
            rs += __shfl_xor(rs, 1); rs += __shfl_xor(rs, 2);
            rs += __shfl_xor(rs, 4); rs += __shfl_xor(rs, 8);
            l_run[r] = l_run[r] * sc + rs;
            m_run[r] = mnew;
            if (l15 == 0) SCb[qrow] = sc;
        }
        __syncthreads();   // B2: P/SC visible; K reads done

        if (t + 1 < 2048 / KT) {
            stageK(t + 1);
            stageV(t + 1, ((t + 1) & 1) ? V1 : V0);
        }

        // ---- PV: rescale acc then O += V P^T
        const char* VB = (t & 1) ? V1 : V0;
        float scv[4];
        #pragma unroll
        for (int nt = 0; nt < 4; ++nt) scv[nt] = SCb[nt * 16 + l15];
        #pragma unroll
        for (int mt = 0; mt < 4; ++mt)
            #pragma unroll
            for (int nt = 0; nt < 4; ++nt)
                #pragma unroll
                for (int r = 0; r < 4; ++r)
                    accp[mt][nt][r] *= scv[nt];
        {
            const int kio = l4 * 16;
            half8 pf[4];
            #pragma unroll
            for (int nt = 0; nt < 4; ++nt) {
                const int qi = nt * 16 + l15;
                pf[nt] = *(const half8*)(PB + qi * 80 + kio);
            }
            #pragma unroll
            for (int mt = 0; mt < 4; ++mt) {
                const int c = w * 64 + mt * 16 + l15;
                half8 vf = *(const half8*)(VB + c * 64 + (kio ^ ((c & 3) << 4)));
                #pragma unroll
                for (int nt = 0; nt < 4; ++nt)
                    accp[mt][nt] = MFMA16(vf, pf[nt], accp[mt][nt]);
            }
        }
    }

    // ---- epilogue: write UNNORMALIZED partial O [q][c] + (m,l)
    float* __restrict__ Op = khalf ? OpB : OpA;
    const size_t obase = (size_t)b * HW + q0;
    const size_t mlbase = ((size_t)(khalf * BATCH + b) * HW + q0);
    #pragma unroll
    for (int nt = 0; nt < 4; ++nt) {
        const int q = nt * 16 + l15;
        #pragma unroll
        for (int mt = 0; mt < 4; ++mt) {
            const size_t g = (obase + q) * C_DIM + w * 64 + mt * 16 + l4 * 4;
            *(f32x4*)(Op + g) = accp[mt][nt];
        }
    }
    if (l15 == 0) {
        #pragma unroll
        for (int r = 0; r < 4; ++r) {
            const int q = w * 16 + l4 * 4 + r;
            ml[mlbase + q] = make_float2(m_run[r], l_run[r]);
        }
    }
}

// ---------------------------------------------------------------------------
// merge: combine the two k-half partials -> frsT hi/lo fp16 [b][q][c]
// ---------------------------------------------------------------------------
__global__ __launch_bounds__(256) void merge_halves(
    const float* __restrict__ OpA, const float* __restrict__ OpB,
    const float2* __restrict__ ml,
    _Float16* __restrict__ fh, _Float16* __restrict__ fl)
{
    const int raw = blockIdx.x;          // 256 WGs
    const int b = raw >> 6;
    const int q0 = (raw & 63) * 64;
    const int tid = threadIdx.x;
    const int q = q0 + (tid >> 2);
    const int cs = (tid & 3) * 64;

    const size_t iq = (size_t)b * HW + q;
    const float2 ml0 = ml[iq];
    const float2 ml1 = ml[(size_t)BATCH * HW + iq];
    const float M = fmaxf(ml0.x, ml1.x);
    const float e0 = exp2f((ml0.x - M) * LOG2E);
    const float e1 = exp2f((ml1.x - M) * LOG2E);
    const float rden = 1.0f / (ml0.y * e0 + ml1.y * e1);

    #pragma unroll
    for (int i = 0; i < 16; ++i) {
        const size_t g = iq * C_DIM + cs + i * 4;
        f32x4 a = *(const f32x4*)(OpA + g);
        f32x4 c = *(const f32x4*)(OpB + g);
        _Float16 hb[4], lb[4];
        #pragma unroll
        for (int r = 0; r < 4; ++r) {
            float v = (a[r] * e0 + c[r] * e1) * rden;
            _Float16 h = (_Float16)v;
            hb[r] = h;
            lb[r] = (_Float16)(v - (float)h);
        }
        *(uint2*)(fh + g) = *(uint2*)hb;
        *(uint2*)(fl + g) = *(uint2*)lb;
    }
}

// ---------------------------------------------------------------------------
// Workspace plan (slot = one fp16 tensor = 2*NE bytes = 8 MiB; total 57.25 MiB,
// safely under the 64 MiB proven by R1). Live-range overlays:
//   s0,s1: fccT(h,l) -> kT(h,l) -> frsT(h,l)
//   s2,s3: fssT(h,l) -> OpartA (f32, 16 MiB)
//   s4,s5: qT(h,l)    s6: vhb    s7: ml(256K) + Wh4(512K) + Wl4(512K)
//   OpartB (khalf=1) lives in d_out (16 MiB), consumed by merge before the
//   final conv overwrites d_out.
// ---------------------------------------------------------------------------
extern "C" void kernel_launch(void* const* d_in, const int* in_sizes, int n_in,
                              void* d_out, int out_size, void* d_ws, size_t ws_size,
                              hipStream_t stream)
{
    const float* x_fcc = (const float*)d_in[0];
    const float* x_fss = (const float*)d_in[1];
    const float* w1  = (const float*)d_in[2];
    const float* b1  = (const float*)d_in[3];
    const float* w2  = (const float*)d_in[4];
    const float* b2  = (const float*)d_in[5];
    const float* w3  = (const float*)d_in[6];
    const float* b3  = (const float*)d_in[7];
    const float* wrs = (const float*)d_in[8];
    const float* brs = (const float*)d_in[9];
    float* out = (float*)d_out;

    const size_t NE = (size_t)BATCH * C_DIM * HW;   // 4,194,304
    const size_t SL = 2 * NE;                       // 8 MiB slot
    char* ws = (char*)d_ws;
    _Float16* fccTh = (_Float16*)(ws + 0 * SL);
    _Float16* fccTl = (_Float16*)(ws + 1 * SL);
    _Float16* fssTh = (_Float16*)(ws + 2 * SL);
    _Float16* fssTl = (_Float16*)(ws + 3 * SL);
    _Float16* qTh   = (_Float16*)(ws + 4 * SL);
    _Float16* qTl   = (_Float16*)(ws + 5 * SL);
    _Float16* kTh   = (_Float16*)(ws + 0 * SL);   // overlay fccT (dead)
    _Float16* kTl   = (_Float16*)(ws + 1 * SL);
    _Float16* vhb   = (_Float16*)(ws + 6 * SL);
    float*    OpA   = (float*)   (ws + 2 * SL);   // overlay fssT (dead), 16 MiB
    float*    OpB   = out;                        // d_out as scratch, 16 MiB
    float2*   mlb   = (float2*)  (ws + 7 * SL);   // 256 KiB
    _Float16* Wh4   = (_Float16*)(ws + 7 * SL + 262144);
    _Float16* Wl4   = (_Float16*)(ws + 7 * SL + 262144 + 524288);
    _Float16* frsTh = (_Float16*)(ws + 0 * SL);   // overlay kT (dead)
    _Float16* frsTl = (_Float16*)(ws + 1 * SL);

    // 1) transpose+split inputs
    dim3 tg(HW / 64, C_DIM / 64, BATCH);
    cvt_tsplit<<<tg, 256, 0, stream>>>(x_fcc, fccTh, fccTl);
    cvt_tsplit<<<tg, 256, 0, stream>>>(x_fss, fssTh, fssTl);
    // 2) split weights
    wsplit<<<dim3(256, 4), 256, 0, stream>>>(w1, w2, w3, wrs, Wh4, Wl4);

    // 3) convs via MFMA (q first so fccT dies before kT overlays it)
    dim3 cg(BATCH * HW / 128, C_DIM / 64);
    conv_mfma<0><<<cg, 256, 0, stream>>>(Wh4,           Wl4,           fccTh, fccTl, b1,
                                         nullptr, nullptr, qTh, qTl);
    conv_mfma<0><<<cg, 256, 0, stream>>>(Wh4 + 65536,   Wl4 + 65536,   fssTh, fssTl, b2,
                                         nullptr, nullptr, kTh, kTl);
    conv_mfma<1><<<cg, 256, 0, stream>>>(Wh4 + 2*65536, Wl4 + 2*65536, fssTh, fssTl, b3,
                                         nullptr, nullptr, vhb, nullptr);

    // 4) attention (k-split x2), then merge
    attn_mfma<<<dim3(512), 256, 0, stream>>>(qTh, qTl, kTh, kTl, vhb, OpA, OpB, mlb);
    merge_halves<<<dim3(256), 256, 0, stream>>>(OpA, OpB, mlb, frsTh, frsTl);

    // 5) final conv + bias + residual
    conv_mfma<2><<<cg, 256, 0, stream>>>(Wh4 + 3*65536, Wl4 + 3*65536, frsTh, frsTl, brs,
                                         x_fcc, out, nullptr, nullptr);
}